// Round 1
// 161.412 us; speedup vs baseline: 1.2551x; 1.2551x over previous
//
#include <hip/hip_runtime.h>

#define HWSZ 16384      // H*W
#define Wd 128
#define Hd 128
#define Dd 48
#define Cc 32
#define Gg 8
#define Vv 5
#define DHW (Dd*HWSZ)   // 786432

// ---------------- kernel 1: proj matrices (4 views x 3x4) ----------------
__global__ void k_proj(const float* __restrict__ am, const float* __restrict__ ainv,
                       const int* __restrict__ idx, float* __restrict__ proj) {
    int t = threadIdx.x;
    if (t >= 4) return;
    int i0 = idx[0];
    int ii = idx[t + 1];
    const float* A  = am   + ii * 16;
    const float* Mi = ainv + i0 * 16;
    for (int r = 0; r < 3; ++r)
        for (int c = 0; c < 4; ++c) {
            float s = 0.f;
            for (int k = 0; k < 4; ++k) s += A[r*4+k] * Mi[k*4+c];
            proj[t*12 + r*4 + c] = s;
        }
}

// ---------------- kernel 2: transpose (C,H,W) -> (H,W,C), LDS-tiled -------
// 64 pixels per block; coalesced global reads AND writes via LDS tile.
__global__ __launch_bounds__(256) void k_transpose(const float* __restrict__ feats,
                                                   const int* __restrict__ idx,
                                                   float* __restrict__ refT,
                                                   float* __restrict__ srcT) {
    __shared__ float tile[Cc][64 + 1];   // +1 pad: conflict-free col reads
    int t = threadIdx.x;
    int slot = blockIdx.x >> 8;          // 256 blocks per slot (16384/64)
    int px0  = (blockIdx.x & 255) << 6;  // 64 px per block
    int v = idx[slot];
    const float* s = feats + (size_t)v * Cc * HWSZ + px0;
    int cr = t >> 6;                     // 0..3
    int pr = t & 63;
#pragma unroll
    for (int k = 0; k < 8; ++k) {
        int c = cr + k * 4;
        tile[c][pr] = s[(size_t)c * HWSZ + pr];
    }
    __syncthreads();
    float* dbase = (slot == 0) ? (refT + ((size_t)px0 << 5))
                               : (srcT + (size_t)(slot - 1) * Cc * HWSZ + ((size_t)px0 << 5));
    int cw = t & 31;
    int pw = t >> 5;                     // 0..7
#pragma unroll
    for (int k = 0; k < 8; ++k) {
        int p = pw + k * 8;
        dbase[((size_t)p << 5) + cw] = tile[cw][p];
    }
}

// ---------------- kernel 3 (TR path): warp + group correlation ------------
// 8 lanes per pixel (one per group). Each corner gather: 8-lane cluster reads
// one full 128-B line (pixel's 32 channels) -> fully coalesced, no divergent
// line amplification. Accumulation order matches the old kernel exactly.
__global__ __launch_bounds__(256) void k_volume8(const float* __restrict__ srcT,
                                                 const float* __restrict__ refT,
                                                 const float* __restrict__ dvals,
                                                 const float* __restrict__ proj,
                                                 float* __restrict__ volume) {
    __shared__ float P[48];
    int t = threadIdx.x;
    if (t < 48) P[t] = proj[t];
    __syncthreads();

    int g = t & 7;
    int dpix = blockIdx.x * 32 + (t >> 3);   // d*HWSZ + h*Wd + w
    int w = dpix & (Wd - 1);
    int h = (dpix >> 7) & (Hd - 1);
    int pix = dpix & (HWSZ - 1);
    float fx = (float)w, fy = (float)h;
    float dep = dvals[dpix];

    // reference slice for this group (4 channels)
    float4 r4 = *(const float4*)(refT + ((size_t)pix << 5) + (g << 2));

    float4 a4 = make_float4(0.f, 0.f, 0.f, 0.f);

#pragma unroll
    for (int v = 0; v < 4; ++v) {
        const float* p = &P[v * 12];
        float sx = (p[0]*fx + p[1]*fy + p[2])  * dep + p[3];
        float sy = (p[4]*fx + p[5]*fy + p[6])  * dep + p[7];
        float sz = (p[8]*fx + p[9]*fy + p[10]) * dep + p[11];
        sz = (fabsf(sz) < 1e-6f) ? 1e-6f : sz;
        float gx = sx / sz, gy = sy / sz;

        float x0f = floorf(gx), y0f = floorf(gy);
        float wx1 = gx - x0f, wx0 = 1.f - wx1;
        float wy1 = gy - y0f, wy0 = 1.f - wy1;
        float x1f = x0f + 1.f, y1f = y0f + 1.f;
        bool xi0 = (x0f >= 0.f) && (x0f <= (float)(Wd-1));
        bool xi1 = (x1f >= 0.f) && (x1f <= (float)(Wd-1));
        bool yi0 = (y0f >= 0.f) && (y0f <= (float)(Hd-1));
        bool yi1 = (y1f >= 0.f) && (y1f <= (float)(Hd-1));
        float w00 = wx0*wy0 * ((xi0 && yi0) ? 1.f : 0.f);
        float w10 = wx1*wy0 * ((xi1 && yi0) ? 1.f : 0.f);
        float w01 = wx0*wy1 * ((xi0 && yi1) ? 1.f : 0.f);
        float w11 = wx1*wy1 * ((xi1 && yi1) ? 1.f : 0.f);
        int x0 = (int)fminf(fmaxf(x0f, 0.f), (float)(Wd-1));
        int x1 = (int)fminf(fmaxf(x1f, 0.f), (float)(Wd-1));
        int y0 = (int)fminf(fmaxf(y0f, 0.f), (float)(Hd-1));
        int y1 = (int)fminf(fmaxf(y1f, 0.f), (float)(Hd-1));

        const float* base = srcT + (size_t)v * Cc * HWSZ + (g << 2);
        float4 t00 = *(const float4*)(base + ((size_t)(y0*Wd + x0) << 5));
        float4 t10 = *(const float4*)(base + ((size_t)(y0*Wd + x1) << 5));
        float4 t01 = *(const float4*)(base + ((size_t)(y1*Wd + x0) << 5));
        float4 t11 = *(const float4*)(base + ((size_t)(y1*Wd + x1) << 5));
        a4.x += t00.x*w00 + t10.x*w10 + t01.x*w01 + t11.x*w11;
        a4.y += t00.y*w00 + t10.y*w10 + t01.y*w01 + t11.y*w11;
        a4.z += t00.z*w00 + t10.z*w10 + t01.z*w01 + t11.z*w11;
        a4.w += t00.w*w00 + t10.w*w10 + t01.w*w01 + t11.w*w11;
    }

    float s = r4.x*a4.x + r4.y*a4.y + r4.z*a4.z + r4.w*a4.w;
    volume[(size_t)g * DHW + dpix] = s * (1.f / 16.f);   // /(C/G)=4 then /(V-1)=4
}

// ---------------- kernel 3 (fallback, no workspace): original layout ------
__global__ __launch_bounds__(256) void k_volume_fb(const float* __restrict__ featsrc,
                                                   const int* __restrict__ idx,
                                                   const float* __restrict__ dvals,
                                                   const float* __restrict__ proj,
                                                   float* __restrict__ volume) {
    __shared__ float P[48];
    __shared__ int sidx[5];
    int t = threadIdx.x;
    if (t < 48) P[t] = proj[t];
    if (t < 5)  sidx[t] = idx[t];
    __syncthreads();

    int tid = blockIdx.x * 256 + t;
    int w = tid & (Wd - 1);
    int h = (tid >> 7) & (Hd - 1);
    int pix = tid & (HWSZ - 1);
    float fx = (float)w, fy = (float)h;
    float dep = dvals[tid];

    float acc[Cc];
#pragma unroll
    for (int c = 0; c < Cc; ++c) acc[c] = 0.f;

#pragma unroll 1
    for (int v = 0; v < 4; ++v) {
        const float* p = &P[v * 12];
        float sx = (p[0]*fx + p[1]*fy + p[2])  * dep + p[3];
        float sy = (p[4]*fx + p[5]*fy + p[6])  * dep + p[7];
        float sz = (p[8]*fx + p[9]*fy + p[10]) * dep + p[11];
        sz = (fabsf(sz) < 1e-6f) ? 1e-6f : sz;
        float gx = sx / sz, gy = sy / sz;

        float x0f = floorf(gx), y0f = floorf(gy);
        float wx1 = gx - x0f, wx0 = 1.f - wx1;
        float wy1 = gy - y0f, wy0 = 1.f - wy1;
        float x1f = x0f + 1.f, y1f = y0f + 1.f;
        bool xi0 = (x0f >= 0.f) && (x0f <= (float)(Wd-1));
        bool xi1 = (x1f >= 0.f) && (x1f <= (float)(Wd-1));
        bool yi0 = (y0f >= 0.f) && (y0f <= (float)(Hd-1));
        bool yi1 = (y1f >= 0.f) && (y1f <= (float)(Hd-1));
        float w00 = wx0*wy0 * ((xi0 && yi0) ? 1.f : 0.f);
        float w10 = wx1*wy0 * ((xi1 && yi0) ? 1.f : 0.f);
        float w01 = wx0*wy1 * ((xi0 && yi1) ? 1.f : 0.f);
        float w11 = wx1*wy1 * ((xi1 && yi1) ? 1.f : 0.f);
        int x0 = (int)fminf(fmaxf(x0f, 0.f), (float)(Wd-1));
        int x1 = (int)fminf(fmaxf(x1f, 0.f), (float)(Wd-1));
        int y0 = (int)fminf(fmaxf(y0f, 0.f), (float)(Hd-1));
        int y1 = (int)fminf(fmaxf(y1f, 0.f), (float)(Hd-1));

        int vv = sidx[v + 1];
        const float* base = featsrc + (size_t)vv * Cc * HWSZ;
        int o00 = y0*Wd + x0, o10 = y0*Wd + x1, o01 = y1*Wd + x0, o11 = y1*Wd + x1;
#pragma unroll
        for (int c = 0; c < Cc; ++c) {
            const float* bc = base + (size_t)c * HWSZ;
            acc[c] += bc[o00]*w00 + bc[o10]*w10 + bc[o01]*w01 + bc[o11]*w11;
        }
    }

    float ref[Cc];
    int v0 = sidx[0];
    const float* rb = featsrc + (size_t)v0 * Cc * HWSZ + pix;
#pragma unroll
    for (int c = 0; c < Cc; ++c) ref[c] = rb[(size_t)c * HWSZ];
#pragma unroll
    for (int g = 0; g < Gg; ++g) {
        float s = ref[g*4+0]*acc[g*4+0] + ref[g*4+1]*acc[g*4+1]
                + ref[g*4+2]*acc[g*4+2] + ref[g*4+3]*acc[g*4+3];
        volume[(size_t)g * DHW + tid] = s * (1.f / 16.f);
    }
}

// ---------------- kernel 4: 3D conv (G->1, 3x3x3, SAME) -------------------
__global__ __launch_bounds__(256) void k_conv(const float* __restrict__ volume,
                                              const float* __restrict__ cw,
                                              const float* __restrict__ cb,
                                              float* __restrict__ dp) {
    __shared__ float Wk[216];
    __shared__ float bias;
    int t = threadIdx.x;
    if (t < 216) Wk[t] = cw[t];
    if (t == 0) bias = cb[0];
    __syncthreads();

    int tid = blockIdx.x * 256 + t;
    int w = tid & (Wd - 1);
    int h = (tid >> 7) & (Hd - 1);
    int d = tid >> 14;
    float s = 0.f;
    for (int g = 0; g < Gg; ++g) {
        const float* vg = volume + (size_t)g * DHW;
#pragma unroll
        for (int dz = -1; dz <= 1; ++dz) {
            int dd = d + dz;
            if (dd < 0 || dd >= Dd) continue;
#pragma unroll
            for (int dy = -1; dy <= 1; ++dy) {
                int hh = h + dy;
                if (hh < 0 || hh >= Hd) continue;
#pragma unroll
                for (int dx = -1; dx <= 1; ++dx) {
                    int ww = w + dx;
                    if (ww < 0 || ww >= Wd) continue;
                    s += vg[(size_t)dd*HWSZ + hh*Wd + ww]
                       * Wk[((g*3 + dz + 1)*3 + (dy + 1))*3 + (dx + 1)];
                }
            }
        }
    }
    dp[tid] = s + bias;
}

// ---------------- kernel 5: softmax over D + expected depth ---------------
__global__ __launch_bounds__(256) void k_depth(const float* __restrict__ dp,
                                               const float* __restrict__ dvals,
                                               float* __restrict__ out) {
    int pix = blockIdx.x * 256 + threadIdx.x;
    float p[Dd];
#pragma unroll
    for (int d = 0; d < Dd; ++d) p[d] = dp[(size_t)d * HWSZ + pix];
    float m = p[0];
#pragma unroll
    for (int d = 1; d < Dd; ++d) m = fmaxf(m, p[d]);
    float se = 0.f, acc = 0.f;
#pragma unroll
    for (int d = 0; d < Dd; ++d) {
        float e = __expf(p[d] - m);
        se += e;
        acc += e * dvals[(size_t)d * HWSZ + pix];
    }
    out[pix] = acc / se;
}

extern "C" void kernel_launch(void* const* d_in, const int* in_sizes, int n_in,
                              void* d_out, int out_size, void* d_ws, size_t ws_size,
                              hipStream_t stream) {
    const float* feats = (const float*)d_in[0];
    const float* am    = (const float*)d_in[1];
    const float* ainv  = (const float*)d_in[2];
    const float* dvals = (const float*)d_in[3];
    const float* cw    = (const float*)d_in[4];
    const float* cb    = (const float*)d_in[5];
    const int*   idx   = (const int*)d_in[6];

    float* out    = (float*)d_out;
    float* volume = out;                         // G*D*H*W
    float* depth  = out + (size_t)Gg * DHW;      // H*W

    float* ws   = (float*)d_ws;
    float* proj = ws;                            // 48 floats (pad to 256)
    float* dp   = ws + 256;                      // DHW floats
    float* refT = ws + 256 + DHW;                // Cc*HWSZ floats
    float* srcT = refT + (size_t)Cc * HWSZ;      // 4*Cc*HWSZ floats
    size_t need = (256 + (size_t)DHW + (size_t)Cc * HWSZ * 5) * sizeof(float);
    bool tr = ws_size >= need;

    k_proj<<<dim3(1), dim3(64), 0, stream>>>(am, ainv, idx, proj);
    if (tr) {
        k_transpose<<<dim3((Vv * HWSZ) / 64), dim3(256), 0, stream>>>(feats, idx, refT, srcT);
        k_volume8<<<dim3(DHW / 32), dim3(256), 0, stream>>>(srcT, refT, dvals, proj, volume);
    } else {
        k_volume_fb<<<dim3(DHW / 256), dim3(256), 0, stream>>>(feats, idx, dvals, proj, volume);
    }
    k_conv<<<dim3(DHW / 256), dim3(256), 0, stream>>>(volume, cw, cb, dp);
    k_depth<<<dim3(HWSZ / 256), dim3(256), 0, stream>>>(dp, dvals, depth);
}

// Round 2
// 107.799 us; speedup vs baseline: 1.8794x; 1.4973x over previous
//
#include <hip/hip_runtime.h>

#define HWSZ 16384      // H*W
#define Wd 128
#define Hd 128
#define Dd 48
#define Cc 32
#define Gg 8
#define Vv 5
#define DHW (Dd*HWSZ)   // 786432

typedef float float4a __attribute__((ext_vector_type(4), aligned(4)));

// ---------------- kernel 1: proj matrices (4 views x 3x4) ----------------
__global__ void k_proj(const float* __restrict__ am, const float* __restrict__ ainv,
                       const int* __restrict__ idx, float* __restrict__ proj) {
    int t = threadIdx.x;
    if (t >= 4) return;
    int i0 = idx[0];
    int ii = idx[t + 1];
    const float* A  = am   + ii * 16;
    const float* Mi = ainv + i0 * 16;
    for (int r = 0; r < 3; ++r)
        for (int c = 0; c < 4; ++c) {
            float s = 0.f;
            for (int k = 0; k < 4; ++k) s += A[r*4+k] * Mi[k*4+c];
            proj[t*12 + r*4 + c] = s;
        }
}

// ---------------- kernel 2: transpose (C,H,W) -> (H,W,C), LDS-tiled -------
__global__ __launch_bounds__(256) void k_transpose(const float* __restrict__ feats,
                                                   const int* __restrict__ idx,
                                                   float* __restrict__ refT,
                                                   float* __restrict__ srcT) {
    __shared__ float tile[Cc][64 + 1];
    int t = threadIdx.x;
    int slot = blockIdx.x >> 8;
    int px0  = (blockIdx.x & 255) << 6;
    int v = idx[slot];
    const float* s = feats + (size_t)v * Cc * HWSZ + px0;
    int cr = t >> 6;
    int pr = t & 63;
#pragma unroll
    for (int k = 0; k < 8; ++k) {
        int c = cr + k * 4;
        tile[c][pr] = s[(size_t)c * HWSZ + pr];
    }
    __syncthreads();
    float* dbase = (slot == 0) ? (refT + ((size_t)px0 << 5))
                               : (srcT + (size_t)(slot - 1) * Cc * HWSZ + ((size_t)px0 << 5));
    int cw = t & 31;
    int pw = t >> 5;
#pragma unroll
    for (int k = 0; k < 8; ++k) {
        int p = pw + k * 8;
        dbase[((size_t)p << 5) + cw] = tile[cw][p];
    }
}

// ---------------- kernel 3 (TR path): warp + group correlation ------------
__global__ __launch_bounds__(256) void k_volume8(const float* __restrict__ srcT,
                                                 const float* __restrict__ refT,
                                                 const float* __restrict__ dvals,
                                                 const float* __restrict__ proj,
                                                 float* __restrict__ volume) {
    __shared__ float P[48];
    int t = threadIdx.x;
    if (t < 48) P[t] = proj[t];
    __syncthreads();

    int g = t & 7;
    int dpix = blockIdx.x * 32 + (t >> 3);
    int w = dpix & (Wd - 1);
    int h = (dpix >> 7) & (Hd - 1);
    int pix = dpix & (HWSZ - 1);
    float fx = (float)w, fy = (float)h;
    float dep = dvals[dpix];

    float4 r4 = *(const float4*)(refT + ((size_t)pix << 5) + (g << 2));
    float4 a4 = make_float4(0.f, 0.f, 0.f, 0.f);

#pragma unroll
    for (int v = 0; v < 4; ++v) {
        const float* p = &P[v * 12];
        float sx = (p[0]*fx + p[1]*fy + p[2])  * dep + p[3];
        float sy = (p[4]*fx + p[5]*fy + p[6])  * dep + p[7];
        float sz = (p[8]*fx + p[9]*fy + p[10]) * dep + p[11];
        sz = (fabsf(sz) < 1e-6f) ? 1e-6f : sz;
        float gx = sx / sz, gy = sy / sz;

        float x0f = floorf(gx), y0f = floorf(gy);
        float wx1 = gx - x0f, wx0 = 1.f - wx1;
        float wy1 = gy - y0f, wy0 = 1.f - wy1;
        float x1f = x0f + 1.f, y1f = y0f + 1.f;
        bool xi0 = (x0f >= 0.f) && (x0f <= (float)(Wd-1));
        bool xi1 = (x1f >= 0.f) && (x1f <= (float)(Wd-1));
        bool yi0 = (y0f >= 0.f) && (y0f <= (float)(Hd-1));
        bool yi1 = (y1f >= 0.f) && (y1f <= (float)(Hd-1));
        float w00 = wx0*wy0 * ((xi0 && yi0) ? 1.f : 0.f);
        float w10 = wx1*wy0 * ((xi1 && yi0) ? 1.f : 0.f);
        float w01 = wx0*wy1 * ((xi0 && yi1) ? 1.f : 0.f);
        float w11 = wx1*wy1 * ((xi1 && yi1) ? 1.f : 0.f);
        int x0 = (int)fminf(fmaxf(x0f, 0.f), (float)(Wd-1));
        int x1 = (int)fminf(fmaxf(x1f, 0.f), (float)(Wd-1));
        int y0 = (int)fminf(fmaxf(y0f, 0.f), (float)(Hd-1));
        int y1 = (int)fminf(fmaxf(y1f, 0.f), (float)(Hd-1));

        const float* base = srcT + (size_t)v * Cc * HWSZ + (g << 2);
        float4 t00 = *(const float4*)(base + ((size_t)(y0*Wd + x0) << 5));
        float4 t10 = *(const float4*)(base + ((size_t)(y0*Wd + x1) << 5));
        float4 t01 = *(const float4*)(base + ((size_t)(y1*Wd + x0) << 5));
        float4 t11 = *(const float4*)(base + ((size_t)(y1*Wd + x1) << 5));
        a4.x += t00.x*w00 + t10.x*w10 + t01.x*w01 + t11.x*w11;
        a4.y += t00.y*w00 + t10.y*w10 + t01.y*w01 + t11.y*w11;
        a4.z += t00.z*w00 + t10.z*w10 + t01.z*w01 + t11.z*w11;
        a4.w += t00.w*w00 + t10.w*w10 + t01.w*w01 + t11.w*w11;
    }

    float s = r4.x*a4.x + r4.y*a4.y + r4.z*a4.z + r4.w*a4.w;
    volume[(size_t)g * DHW + dpix] = s * (1.f / 16.f);
}

// ---------------- kernel 3 (fallback, no workspace): original layout ------
__global__ __launch_bounds__(256) void k_volume_fb(const float* __restrict__ featsrc,
                                                   const int* __restrict__ idx,
                                                   const float* __restrict__ dvals,
                                                   const float* __restrict__ proj,
                                                   float* __restrict__ volume) {
    __shared__ float P[48];
    __shared__ int sidx[5];
    int t = threadIdx.x;
    if (t < 48) P[t] = proj[t];
    if (t < 5)  sidx[t] = idx[t];
    __syncthreads();

    int tid = blockIdx.x * 256 + t;
    int w = tid & (Wd - 1);
    int h = (tid >> 7) & (Hd - 1);
    int pix = tid & (HWSZ - 1);
    float fx = (float)w, fy = (float)h;
    float dep = dvals[tid];

    float acc[Cc];
#pragma unroll
    for (int c = 0; c < Cc; ++c) acc[c] = 0.f;

#pragma unroll 1
    for (int v = 0; v < 4; ++v) {
        const float* p = &P[v * 12];
        float sx = (p[0]*fx + p[1]*fy + p[2])  * dep + p[3];
        float sy = (p[4]*fx + p[5]*fy + p[6])  * dep + p[7];
        float sz = (p[8]*fx + p[9]*fy + p[10]) * dep + p[11];
        sz = (fabsf(sz) < 1e-6f) ? 1e-6f : sz;
        float gx = sx / sz, gy = sy / sz;

        float x0f = floorf(gx), y0f = floorf(gy);
        float wx1 = gx - x0f, wx0 = 1.f - wx1;
        float wy1 = gy - y0f, wy0 = 1.f - wy1;
        float x1f = x0f + 1.f, y1f = y0f + 1.f;
        bool xi0 = (x0f >= 0.f) && (x0f <= (float)(Wd-1));
        bool xi1 = (x1f >= 0.f) && (x1f <= (float)(Wd-1));
        bool yi0 = (y0f >= 0.f) && (y0f <= (float)(Hd-1));
        bool yi1 = (y1f >= 0.f) && (y1f <= (float)(Hd-1));
        float w00 = wx0*wy0 * ((xi0 && yi0) ? 1.f : 0.f);
        float w10 = wx1*wy0 * ((xi1 && yi0) ? 1.f : 0.f);
        float w01 = wx0*wy1 * ((xi0 && yi1) ? 1.f : 0.f);
        float w11 = wx1*wy1 * ((xi1 && yi1) ? 1.f : 0.f);
        int x0 = (int)fminf(fmaxf(x0f, 0.f), (float)(Wd-1));
        int x1 = (int)fminf(fmaxf(x1f, 0.f), (float)(Wd-1));
        int y0 = (int)fminf(fmaxf(y0f, 0.f), (float)(Hd-1));
        int y1 = (int)fminf(fmaxf(y1f, 0.f), (float)(Hd-1));

        int vv = sidx[v + 1];
        const float* base = featsrc + (size_t)vv * Cc * HWSZ;
        int o00 = y0*Wd + x0, o10 = y0*Wd + x1, o01 = y1*Wd + x0, o11 = y1*Wd + x1;
#pragma unroll
        for (int c = 0; c < Cc; ++c) {
            const float* bc = base + (size_t)c * HWSZ;
            acc[c] += bc[o00]*w00 + bc[o10]*w10 + bc[o01]*w01 + bc[o11]*w11;
        }
    }

    float ref[Cc];
    int v0 = sidx[0];
    const float* rb = featsrc + (size_t)v0 * Cc * HWSZ + pix;
#pragma unroll
    for (int c = 0; c < Cc; ++c) ref[c] = rb[(size_t)c * HWSZ];
#pragma unroll
    for (int g = 0; g < Gg; ++g) {
        float s = ref[g*4+0]*acc[g*4+0] + ref[g*4+1]*acc[g*4+1]
                + ref[g*4+2]*acc[g*4+2] + ref[g*4+3]*acc[g*4+3];
        volume[(size_t)g * DHW + tid] = s * (1.f / 16.f);
    }
}

// ---------------- kernel 4: 3D conv (G->1, 3x3x3, SAME), Wtile=4 ----------
// Each thread computes 4 consecutive w outputs at one (d,h). Per (g,plane,row)
// two overlapping float4 loads supply all 6 needed values; w-borders fixed
// with branch-free selects; h-borders diverge only in edge waves; d-borders
// are block-uniform branches.
__global__ __launch_bounds__(256) void k_conv(const float* __restrict__ volume,
                                              const float* __restrict__ cw,
                                              const float* __restrict__ cb,
                                              float* __restrict__ dp) {
    __shared__ float Wk[216];
    __shared__ float bias;
    int t = threadIdx.x;
    if (t < 216) Wk[t] = cw[t];
    if (t == 0) bias = cb[0];
    __syncthreads();

    int T  = blockIdx.x * 256 + t;
    int wg = T & 31;
    int w0 = wg << 2;
    int h  = (T >> 5) & 127;
    int d  = T >> 12;                 // uniform per block (4096 threads per d)
    bool left  = (w0 == 0);
    bool right = (w0 == 124);
    int c0 = left  ? 0   : w0 - 1;
    int c1 = right ? 124 : w0 + 1;

    float acc0 = 0.f, acc1 = 0.f, acc2 = 0.f, acc3 = 0.f;

#pragma unroll 1
    for (int g = 0; g < Gg; ++g) {
        float wt[27];
#pragma unroll
        for (int j = 0; j < 27; ++j) wt[j] = Wk[g * 27 + j];
        const float* vg = volume + (size_t)g * DHW;
#pragma unroll
        for (int pz = 0; pz < 3; ++pz) {
            int dd = d - 1 + pz;
            if (dd < 0 || dd >= Dd) continue;       // block-uniform
            const float* vp = vg + (size_t)dd * HWSZ;
#pragma unroll
            for (int dy = 0; dy < 3; ++dy) {
                int hh = h - 1 + dy;
                if (hh < 0 || hh >= Hd) continue;   // edge-wave divergence only
                const float* vr = vp + hh * Wd;
                float4a L0 = *(const float4a*)(vr + c0);
                float4a L1 = *(const float4a*)(vr + c1);
                float n0 = left  ? 0.f  : L0.x;
                float n1 = left  ? L0.x : L0.y;
                float n2 = left  ? L0.y : L0.z;
                float n3 = left  ? L0.z : L0.w;
                float n4 = right ? L1.w : L1.z;
                float n5 = right ? 0.f  : L1.w;
                float wa = wt[pz*9 + dy*3 + 0];
                float wb = wt[pz*9 + dy*3 + 1];
                float wc = wt[pz*9 + dy*3 + 2];
                acc0 += n0*wa + n1*wb + n2*wc;
                acc1 += n1*wa + n2*wb + n3*wc;
                acc2 += n2*wa + n3*wb + n4*wc;
                acc3 += n3*wa + n4*wb + n5*wc;
            }
        }
    }
    size_t o = (size_t)d * HWSZ + (size_t)h * Wd + w0;
    dp[o + 0] = acc0 + bias;
    dp[o + 1] = acc1 + bias;
    dp[o + 2] = acc2 + bias;
    dp[o + 3] = acc3 + bias;
}

// ---------------- kernel 5: softmax over D + expected depth ---------------
__global__ __launch_bounds__(256) void k_depth(const float* __restrict__ dp,
                                               const float* __restrict__ dvals,
                                               float* __restrict__ out) {
    int pix = blockIdx.x * 256 + threadIdx.x;
    float p[Dd];
#pragma unroll
    for (int d = 0; d < Dd; ++d) p[d] = dp[(size_t)d * HWSZ + pix];
    float m = p[0];
#pragma unroll
    for (int d = 1; d < Dd; ++d) m = fmaxf(m, p[d]);
    float se = 0.f, acc = 0.f;
#pragma unroll
    for (int d = 0; d < Dd; ++d) {
        float e = __expf(p[d] - m);
        se += e;
        acc += e * dvals[(size_t)d * HWSZ + pix];
    }
    out[pix] = acc / se;
}

extern "C" void kernel_launch(void* const* d_in, const int* in_sizes, int n_in,
                              void* d_out, int out_size, void* d_ws, size_t ws_size,
                              hipStream_t stream) {
    const float* feats = (const float*)d_in[0];
    const float* am    = (const float*)d_in[1];
    const float* ainv  = (const float*)d_in[2];
    const float* dvals = (const float*)d_in[3];
    const float* cw    = (const float*)d_in[4];
    const float* cb    = (const float*)d_in[5];
    const int*   idx   = (const int*)d_in[6];

    float* out    = (float*)d_out;
    float* volume = out;                         // G*D*H*W
    float* depth  = out + (size_t)Gg * DHW;      // H*W

    float* ws   = (float*)d_ws;
    float* proj = ws;                            // 48 floats (pad to 256)
    float* dp   = ws + 256;                      // DHW floats
    float* refT = ws + 256 + DHW;                // Cc*HWSZ floats
    float* srcT = refT + (size_t)Cc * HWSZ;      // 4*Cc*HWSZ floats
    size_t need = (256 + (size_t)DHW + (size_t)Cc * HWSZ * 5) * sizeof(float);
    bool tr = ws_size >= need;

    k_proj<<<dim3(1), dim3(64), 0, stream>>>(am, ainv, idx, proj);
    if (tr) {
        k_transpose<<<dim3((Vv * HWSZ) / 64), dim3(256), 0, stream>>>(feats, idx, refT, srcT);
        k_volume8<<<dim3(DHW / 32), dim3(256), 0, stream>>>(srcT, refT, dvals, proj, volume);
    } else {
        k_volume_fb<<<dim3(DHW / 256), dim3(256), 0, stream>>>(feats, idx, dvals, proj, volume);
    }
    k_conv<<<dim3(DHW / 1024), dim3(256), 0, stream>>>(volume, cw, cb, dp);
    k_depth<<<dim3(HWSZ / 256), dim3(256), 0, stream>>>(dp, dvals, depth);
}